// Round 4
// baseline (729.806 us; speedup 1.0000x reference)
//
#include <hip/hip_runtime.h>
#include <cstdint>

typedef __attribute__((ext_vector_type(8))) short short8;
typedef __attribute__((ext_vector_type(4))) float f32x4;
typedef unsigned short ushort_t;

#define D_MODEL 1024
#define SEQ     2048
#define NBATCH  4
#define NHEADS  16
#define HDIM    64

__device__ __forceinline__ unsigned short f2bf(float f) {
  unsigned int u = __float_as_uint(f);
  u = u + 0x7fffu + ((u >> 16) & 1u);   // RNE; inputs are finite
  return (unsigned short)(u >> 16);
}

// ---------------- transpose + convert weights ----------------
// out[n][k] = W[k][n] as bf16.  z=0,1,2 -> WTqkv (stacked), z=3 -> WTo
__global__ __launch_bounds__(256) void cvt_w_kernel(const float* __restrict__ Wq,
                                                    const float* __restrict__ Wk,
                                                    const float* __restrict__ Wv,
                                                    const float* __restrict__ Wo,
                                                    ushort_t* __restrict__ WTqkv,
                                                    ushort_t* __restrict__ WTo) {
  __shared__ float tile[64][65];
  const int z = blockIdx.z;
  const float* W = (z == 0) ? Wq : (z == 1) ? Wk : (z == 2) ? Wv : Wo;
  ushort_t* out = (z < 3) ? (WTqkv + (size_t)z * D_MODEL * D_MODEL) : WTo;
  const int k0 = blockIdx.x * 64, n0 = blockIdx.y * 64;
  const int tx = threadIdx.x & 63, ty = threadIdx.x >> 6;
#pragma unroll
  for (int i = 0; i < 16; ++i) {
    int r = ty + i * 4;
    tile[r][tx] = W[(size_t)(k0 + r) * D_MODEL + n0 + tx];
  }
  __syncthreads();
#pragma unroll
  for (int i = 0; i < 16; ++i) {
    int r = ty + i * 4;
    out[(size_t)(n0 + r) * D_MODEL + k0 + tx] = f2bf(tile[tx][r]);
  }
}

// ---------------- fused QKV GEMM ----------------
// X [8192][1024] fp32 (converted to bf16 during staging),
// BT [3072][1024] bf16 (Wq^T|Wk^T|Wv^T rows).
// C[m][n3] scattered: Q,K as [B,H,S,Hd]; V transposed [B,H,Hd,S].
#define BM 128
#define BN 128
#define BK 32

__global__ __launch_bounds__(256) void gemm_qkv_kernel(
    const float* __restrict__ X, const ushort_t* __restrict__ BT,
    const float* __restrict__ bq, const float* __restrict__ bk,
    const float* __restrict__ bv,
    ushort_t* __restrict__ Qb, ushort_t* __restrict__ Kb,
    ushort_t* __restrict__ Vb) {
  __shared__ __align__(16) ushort_t As[BM * BK];
  __shared__ __align__(16) ushort_t Bs[BN * BK];
  const int t = threadIdx.x;
  const int l = t & 63;
  const int w = t >> 6;
  const int m0 = blockIdx.x * BM;
  const int n0 = blockIdx.y * BN;
  const int wm = (w & 1) * 64, wn = (w >> 1) * 64;
  const int lr = l & 15, lg = l >> 4;

  f32x4 acc[4][4] = {};

  for (int k0 = 0; k0 < D_MODEL; k0 += BK) {
#pragma unroll
    for (int i = 0; i < 2; ++i) {
      int chunk = t + i * 256;            // 0..511
      int row = chunk >> 2;
      int c8 = (chunk & 3) * 8;
      // A: fp32 -> bf16 on the fly
      const float* src = X + (size_t)(m0 + row) * D_MODEL + k0 + c8;
      float4 v0 = reinterpret_cast<const float4*>(src)[0];
      float4 v1 = reinterpret_cast<const float4*>(src)[1];
      short8 oa;
      oa[0] = (short)f2bf(v0.x); oa[1] = (short)f2bf(v0.y);
      oa[2] = (short)f2bf(v0.z); oa[3] = (short)f2bf(v0.w);
      oa[4] = (short)f2bf(v1.x); oa[5] = (short)f2bf(v1.y);
      oa[6] = (short)f2bf(v1.z); oa[7] = (short)f2bf(v1.w);
      *reinterpret_cast<short8*>(As + chunk * 8) = oa;
      *reinterpret_cast<short8*>(Bs + chunk * 8) =
          *reinterpret_cast<const short8*>(BT + (size_t)(n0 + row) * D_MODEL + k0 + c8);
    }
    __syncthreads();
    short8 af[4], bfr[4];
#pragma unroll
    for (int m = 0; m < 4; ++m)
      af[m] = *reinterpret_cast<const short8*>(As + (wm + m * 16 + lr) * BK + lg * 8);
#pragma unroll
    for (int n = 0; n < 4; ++n)
      bfr[n] = *reinterpret_cast<const short8*>(Bs + (wn + n * 16 + lr) * BK + lg * 8);
#pragma unroll
    for (int m = 0; m < 4; ++m)
#pragma unroll
      for (int n = 0; n < 4; ++n)
        acc[m][n] = __builtin_amdgcn_mfma_f32_16x16x32_bf16(af[m], bfr[n], acc[m][n], 0, 0, 0);
    __syncthreads();
  }

#pragma unroll
  for (int m = 0; m < 4; ++m)
#pragma unroll
    for (int n = 0; n < 4; ++n) {
      int colg = n0 + wn + n * 16 + lr;     // 0..3071
      int which = colg >> 10;
      int nc = colg & 1023;
      int h = nc >> 6, hd = nc & 63;
      float bias = (which == 0) ? bq[nc] : (which == 1) ? bk[nc] : bv[nc];
#pragma unroll
      for (int r = 0; r < 4; ++r) {
        int rowg = m0 + wm + m * 16 + lg * 4 + r;
        int b = rowg >> 11, s = rowg & 2047;
        int bh = b * NHEADS + h;
        ushort_t v16 = f2bf(acc[m][n][r] + bias);
        if (which == 0)
          Qb[((size_t)bh * SEQ + s) * HDIM + hd] = v16;
        else if (which == 1)
          Kb[((size_t)bh * SEQ + s) * HDIM + hd] = v16;
        else
          Vb[((size_t)bh * HDIM + hd) * SEQ + s] = v16;
      }
    }
}

// ---------------- flash attention ----------------
// grid (64 bh, 32 q-tiles of 64). 4 waves, wave w owns q rows q0+w*16..+15.
__global__ __launch_bounds__(256) void attn_kernel(const ushort_t* __restrict__ Qb,
                                                   const ushort_t* __restrict__ Kb,
                                                   const ushort_t* __restrict__ Vb,
                                                   ushort_t* __restrict__ Ob) {
  __shared__ __align__(16) ushort_t P_lds[4][16 * 64];
  const int t = threadIdx.x, l = t & 63, w = t >> 6;
  const int lr = l & 15, lg = l >> 4;
  const int bh = blockIdx.x;
  const int q0 = blockIdx.y * 64;
  const int b = bh >> 4, h = bh & 15;

  const ushort_t* Qp = Qb + ((size_t)bh * SEQ + q0 + w * 16) * HDIM;
  const ushort_t* Kp = Kb + (size_t)bh * SEQ * HDIM;
  const ushort_t* Vp = Vb + (size_t)bh * HDIM * SEQ;

  short8 aq[2];
#pragma unroll
  for (int kk = 0; kk < 2; ++kk)
    aq[kk] = *reinterpret_cast<const short8*>(Qp + lr * HDIM + kk * 32 + lg * 8);

  f32x4 o[4] = {};
  float mrow[4], lrow[4];
#pragma unroll
  for (int r = 0; r < 4; ++r) { mrow[r] = -INFINITY; lrow[r] = 0.f; }

  for (int kv0 = 0; kv0 < SEQ; kv0 += 64) {
    f32x4 s[4] = {};
#pragma unroll
    for (int n = 0; n < 4; ++n)
#pragma unroll
      for (int kk = 0; kk < 2; ++kk) {
        short8 bk = *reinterpret_cast<const short8*>(
            Kp + (size_t)(kv0 + n * 16 + lr) * HDIM + kk * 32 + lg * 8);
        s[n] = __builtin_amdgcn_mfma_f32_16x16x32_bf16(aq[kk], bk, s[n], 0, 0, 0);
      }
    // scale
#pragma unroll
    for (int n = 0; n < 4; ++n)
#pragma unroll
      for (int r = 0; r < 4; ++r) s[n][r] *= 0.125f;
    // row max across 4 frags then across 16-lane col group
    float tmax[4];
#pragma unroll
    for (int r = 0; r < 4; ++r) {
      tmax[r] = fmaxf(fmaxf(s[0][r], s[1][r]), fmaxf(s[2][r], s[3][r]));
#pragma unroll
      for (int d = 1; d < 16; d <<= 1)
        tmax[r] = fmaxf(tmax[r], __shfl_xor(tmax[r], d, 64));
    }
    float mnew[4], scl[4], psum[4];
#pragma unroll
    for (int r = 0; r < 4; ++r) {
      mnew[r] = fmaxf(mrow[r], tmax[r]);
      scl[r] = __expf(mrow[r] - mnew[r]);
      mrow[r] = mnew[r];
      psum[r] = 0.f;
    }
#pragma unroll
    for (int n = 0; n < 4; ++n)
#pragma unroll
      for (int r = 0; r < 4; ++r) {
        float p = __expf(s[n][r] - mnew[r]);
        s[n][r] = p;
        psum[r] += p;
      }
#pragma unroll
    for (int r = 0; r < 4; ++r) {
#pragma unroll
      for (int d = 1; d < 16; d <<= 1) psum[r] += __shfl_xor(psum[r], d, 64);
      lrow[r] = lrow[r] * scl[r] + psum[r];
    }
#pragma unroll
    for (int n = 0; n < 4; ++n)
#pragma unroll
      for (int r = 0; r < 4; ++r) o[n][r] *= scl[r];
    // P -> LDS (C layout -> A layout via memory)
    ushort_t* Pw = P_lds[w];
#pragma unroll
    for (int n = 0; n < 4; ++n)
#pragma unroll
      for (int r = 0; r < 4; ++r)
        Pw[(lg * 4 + r) * 64 + n * 16 + lr] = f2bf(s[n][r]);
    __syncthreads();
    // PV
#pragma unroll
    for (int kk = 0; kk < 2; ++kk) {
      short8 pa = *reinterpret_cast<const short8*>(Pw + lr * 64 + kk * 32 + lg * 8);
#pragma unroll
      for (int n = 0; n < 4; ++n) {
        short8 bv = *reinterpret_cast<const short8*>(
            Vp + (size_t)(n * 16 + lr) * SEQ + kv0 + kk * 32 + lg * 8);
        o[n] = __builtin_amdgcn_mfma_f32_16x16x32_bf16(pa, bv, o[n], 0, 0, 0);
      }
    }
    __syncthreads();
  }

#pragma unroll
  for (int n = 0; n < 4; ++n)
#pragma unroll
    for (int r = 0; r < 4; ++r) {
      int row = q0 + w * 16 + lg * 4 + r;
      float val = o[n][r] / lrow[r];
      Ob[((size_t)b * SEQ + row) * D_MODEL + h * HDIM + n * 16 + lr] = f2bf(val);
    }
}

// ---------------- output projection GEMM ----------------
__global__ __launch_bounds__(256) void gemm_out_kernel(const ushort_t* __restrict__ A,
                                                       const ushort_t* __restrict__ BT,
                                                       const float* __restrict__ bo,
                                                       float* __restrict__ out) {
  __shared__ __align__(16) ushort_t As[BM * BK];
  __shared__ __align__(16) ushort_t Bs[BN * BK];
  const int t = threadIdx.x;
  const int l = t & 63;
  const int w = t >> 6;
  const int m0 = blockIdx.x * BM;
  const int n0 = blockIdx.y * BN;
  const int wm = (w & 1) * 64, wn = (w >> 1) * 64;
  const int lr = l & 15, lg = l >> 4;

  f32x4 acc[4][4] = {};

  for (int k0 = 0; k0 < D_MODEL; k0 += BK) {
#pragma unroll
    for (int i = 0; i < 2; ++i) {
      int chunk = t + i * 256;
      int row = chunk >> 2;
      int c8 = (chunk & 3) * 8;
      *reinterpret_cast<short8*>(As + chunk * 8) =
          *reinterpret_cast<const short8*>(A + (size_t)(m0 + row) * D_MODEL + k0 + c8);
      *reinterpret_cast<short8*>(Bs + chunk * 8) =
          *reinterpret_cast<const short8*>(BT + (size_t)(n0 + row) * D_MODEL + k0 + c8);
    }
    __syncthreads();
    short8 af[4], bfr[4];
#pragma unroll
    for (int m = 0; m < 4; ++m)
      af[m] = *reinterpret_cast<const short8*>(As + (wm + m * 16 + lr) * BK + lg * 8);
#pragma unroll
    for (int n = 0; n < 4; ++n)
      bfr[n] = *reinterpret_cast<const short8*>(Bs + (wn + n * 16 + lr) * BK + lg * 8);
#pragma unroll
    for (int m = 0; m < 4; ++m)
#pragma unroll
      for (int n = 0; n < 4; ++n)
        acc[m][n] = __builtin_amdgcn_mfma_f32_16x16x32_bf16(af[m], bfr[n], acc[m][n], 0, 0, 0);
    __syncthreads();
  }

#pragma unroll
  for (int m = 0; m < 4; ++m)
#pragma unroll
    for (int n = 0; n < 4; ++n) {
      int colg = n0 + wn + n * 16 + lr;
      float bias = bo[colg];
#pragma unroll
      for (int r = 0; r < 4; ++r) {
        int rowg = m0 + wm + m * 16 + lg * 4 + r;
        out[(size_t)rowg * D_MODEL + colg] = acc[m][n][r] + bias;
      }
    }
}

// ---------------- launch ----------------
extern "C" void kernel_launch(void* const* d_in, const int* in_sizes, int n_in,
                              void* d_out, int out_size, void* d_ws, size_t ws_size,
                              hipStream_t stream) {
  (void)in_sizes; (void)n_in; (void)out_size; (void)ws_size;
  const float* x  = (const float*)d_in[0];
  const float* Wq = (const float*)d_in[1];
  const float* bq = (const float*)d_in[2];
  const float* Wk = (const float*)d_in[3];
  const float* bk = (const float*)d_in[4];
  const float* Wv = (const float*)d_in[5];
  const float* bv = (const float*)d_in[6];
  const float* Wo = (const float*)d_in[7];
  const float* bo = (const float*)d_in[8];
  float* out = (float*)d_out;

  ushort_t* ws    = (ushort_t*)d_ws;
  ushort_t* WTqkv = ws;                       // 3072*1024
  ushort_t* WTo   = WTqkv + 3145728;          // 1024*1024
  ushort_t* Qb    = WTo + 1048576;            // 64*2048*64
  ushort_t* Kb    = Qb + 8388608;
  ushort_t* Vb    = Kb + 8388608;
  ushort_t* Ob    = Vb + 8388608;             // 8192*1024
  // total ws use: 37,748,736 bf16 elems = 75.5 MB

  cvt_w_kernel<<<dim3(16, 16, 4), 256, 0, stream>>>(Wq, Wk, Wv, Wo, WTqkv, WTo);
  gemm_qkv_kernel<<<dim3(64, 24), 256, 0, stream>>>(x, WTqkv, bq, bk, bv, Qb, Kb, Vb);
  attn_kernel<<<dim3(64, 32), 256, 0, stream>>>(Qb, Kb, Vb, Ob);
  gemm_out_kernel<<<dim3(64, 8), 256, 0, stream>>>(Ob, WTo, bo, out);
}